// Round 8
// baseline (234.738 us; speedup 1.0000x reference)
//
#include <hip/hip_runtime.h>
#include <math.h>

#define NB 8
#define MSEG 16
#define PPIX (640*640)
#define PV4 (PPIX/4)          // 102400 float4/int4 groups per batch
#define GRIDX 128             // 1024 blocks total
#define STRIDE (GRIDX*256)    // 32768; 3 full iters = 98304, remainder 4096
#define FULLCOV (3*STRIDE)    // 98304
#define DELTA_AGG 0.5f
#define DELTA_DIS 3.0f

typedef float v2f __attribute__((ext_vector_type(2)));

// ws layout: int counters [16] at byte 0 (zeroed by 64B memset), then floats:
#define OFF_P1 16                          // [NB][80][GRIDX] pass1 partials (value-major)
#define OFF_GC (OFF_P1 + NB*80*GRIDX)      // [NB][80]: 0..63 G (m*4+ch), 64..79 cnt_k
#define OFF_P2 (OFF_GC + NB*80)            // [NB][32][GRIDX] pass2 partials (value-major)

// ---------------- pass 1: segment sums by kern + fused G finalize ----------------
__global__ __launch_bounds__(256, 3) void pass1_kernel(
    const float* __restrict__ preds, const int* __restrict__ targets,
    float* __restrict__ ws, int* __restrict__ ctr) {
  const int n = blockIdx.y, blk = blockIdx.x;
  const int tid = threadIdx.x, lane = tid & 63, w = tid >> 6;

  const float4* __restrict__ pc0 = (const float4*)(preds + ((size_t)n*6 + 2)*PPIX);
  const float4* __restrict__ pc1 = (const float4*)(preds + ((size_t)n*6 + 3)*PPIX);
  const float4* __restrict__ pc2 = (const float4*)(preds + ((size_t)n*6 + 4)*PPIX);
  const float4* __restrict__ pc3 = (const float4*)(preds + ((size_t)n*6 + 5)*PPIX);
  const int4*  __restrict__ kernv = (const int4*)(targets + ((size_t)n*2 + 1)*PPIX);

  v2f acc01[MSEG], acc23[MSEG];
  float cntk[MSEG];
#pragma unroll
  for (int m = 0; m < MSEG; ++m) {
    acc01[m] = (v2f){0.f, 0.f}; acc23[m] = (v2f){0.f, 0.f}; cntk[m] = 0.f;
  }

#define PIX1(K, A0, A1, A2, A3) do {                                \
    int k_ = (K);                                                   \
    v2f p01 = {(A0), (A1)}, p23 = {(A2), (A3)};                     \
    _Pragma("unroll")                                               \
    for (int m = 0; m < MSEG; ++m) {                                \
      float fk = (k_ == m) ? 1.0f : 0.0f;                           \
      v2f fk2 = {fk, fk};                                           \
      acc01[m] = __builtin_elementwise_fma(fk2, p01, acc01[m]);     \
      acc23[m] = __builtin_elementwise_fma(fk2, p23, acc23[m]);     \
      cntk[m] += fk;                                                \
    } } while (0)

#define GRP1(KK, VA, VB, VC, VD) do {                \
    PIX1((KK).x, (VA).x, (VB).x, (VC).x, (VD).x);    \
    PIX1((KK).y, (VA).y, (VB).y, (VC).y, (VD).y);    \
    PIX1((KK).z, (VA).z, (VB).z, (VC).z, (VD).z);    \
    PIX1((KK).w, (VA).w, (VB).w, (VC).w, (VD).w);    \
  } while (0)

  const int base = blk*256 + tid;
  int4 kc = kernv[base];
  float4 va = pc0[base], vb = pc1[base], vc = pc2[base], vd = pc3[base];
  {
    const int p = base + STRIDE;
    int4 kn = kernv[p];
    float4 an = pc0[p], bn = pc1[p], cn = pc2[p], dn = pc3[p];
    GRP1(kc, va, vb, vc, vd);
    kc = kn; va = an; vb = bn; vc = cn; vd = dn;
  }
  {
    const int p = base + 2*STRIDE;
    int4 kn = kernv[p];
    float4 an = pc0[p], bn = pc1[p], cn = pc2[p], dn = pc3[p];
    GRP1(kc, va, vb, vc, vd);
    kc = kn; va = an; vb = bn; vc = cn; vd = dn;
  }
  {
    int4 kr; float4 ar, br, cr, dr;
    const int pr = FULLCOV + blk*32 + (tid & 31);
    if (tid < 32) { kr = kernv[pr]; ar = pc0[pr]; br = pc1[pr]; cr = pc2[pr]; dr = pc3[pr]; }
    GRP1(kc, va, vb, vc, vd);
    if (tid < 32) GRP1(kr, ar, br, cr, dr);
  }
#undef GRP1
#undef PIX1

  float acc[80];
#pragma unroll
  for (int m = 0; m < MSEG; ++m) {
    acc[m]      = acc01[m].x;
    acc[16 + m] = acc01[m].y;
    acc[32 + m] = acc23[m].x;
    acc[48 + m] = acc23[m].y;
    acc[64 + m] = cntk[m];
  }

  // 64-value xor reduce-scatter: lane l ends holding the 64-lane sum of acc[l]
#pragma unroll
  for (int s = 0; s < 6; ++s) {
    const int dist = 32 >> s;
    const bool hi = (lane & dist) != 0;
#pragma unroll
    for (int v = 0; v < (32 >> s); ++v) {
      float keep = hi ? acc[v + (32 >> s)] : acc[v];
      float send = hi ? acc[v] : acc[v + (32 >> s)];
      acc[v] = keep + __shfl_xor(send, dist);
    }
  }
  // 16-value reduce-scatter on cnt_k
  float cn16[16];
#pragma unroll
  for (int m = 0; m < MSEG; ++m) cn16[m] = acc[64 + m];
#pragma unroll
  for (int s = 0; s < 4; ++s) {
    const int dist = 32 >> s;
    const int half = 8 >> s;
    const bool hi = (lane & dist) != 0;
#pragma unroll
    for (int v = 0; v < half; ++v) {
      float keep = hi ? cn16[v + half] : cn16[v];
      float send = hi ? cn16[v] : cn16[v + half];
      cn16[v] = keep + __shfl_xor(send, dist);
    }
  }
  float ckt = cn16[0];
  ckt += __shfl_xor(ckt, 2);
  ckt += __shfl_xor(ckt, 1);

  __shared__ float s_v[4][64];
  __shared__ float s_c[4][16];
  s_v[w][lane] = acc[0];
  if ((lane & 3) == 0) s_c[w][lane >> 2] = ckt;
  __syncthreads();

  // per-block partials, value-major [n][v][blk] for contiguous last-block reads
  if (tid < 64)
    ws[OFF_P1 + ((size_t)n*80 + tid)*GRIDX + blk] =
        s_v[0][tid] + s_v[1][tid] + s_v[2][tid] + s_v[3][tid];
  else if (tid < 80) {
    int i = tid - 64;
    ws[OFF_P1 + ((size_t)n*80 + tid)*GRIDX + blk] =
        s_c[0][i] + s_c[1][i] + s_c[2][i] + s_c[3][i];
  }

  // last block of this batch finalizes G
  __threadfence();
  __shared__ int s_last;
  if (tid == 0) s_last = (atomicAdd(&ctr[n], 1) == GRIDX - 1);
  __syncthreads();
  if (!s_last) return;
  __threadfence();

  __shared__ float raw[80];
  if (tid < 80) {
    const float4* p4 = (const float4*)(ws + OFF_P1 + ((size_t)n*80 + tid)*GRIDX);
    float s = 0.f;
#pragma unroll
    for (int i = 0; i < GRIDX/4; ++i) {
      float4 v = p4[i];
      s += (v.x + v.y) + (v.z + v.w);
    }
    raw[tid] = s;
  }
  __syncthreads();
  if (tid < 64) {
    int ch = tid >> 4, m = tid & 15;
    ws[OFF_GC + n*80 + m*4 + ch] = raw[tid] / fmaxf(raw[64 + m], 1.0f);
  } else if (tid < 80) {
    ws[OFF_GC + n*80 + tid] = raw[tid];   // cnt_k
  }
}

// ---------------- pass 2: agg sums + cnt_t by text + fused final outputs ----------------
__global__ __launch_bounds__(256, 3) void pass2_kernel(
    const float* __restrict__ preds, const int* __restrict__ targets,
    float* __restrict__ ws, int* __restrict__ ctr, float* __restrict__ out) {
  const int n = blockIdx.y, blk = blockIdx.x;
  const int tid = threadIdx.x, lane = tid & 63, w = tid >> 6;

  const float4* __restrict__ pc0 = (const float4*)(preds + ((size_t)n*6 + 2)*PPIX);
  const float4* __restrict__ pc1 = (const float4*)(preds + ((size_t)n*6 + 3)*PPIX);
  const float4* __restrict__ pc2 = (const float4*)(preds + ((size_t)n*6 + 4)*PPIX);
  const float4* __restrict__ pc3 = (const float4*)(preds + ((size_t)n*6 + 5)*PPIX);
  const int4*  __restrict__ textv = (const int4*)(targets + (size_t)n*2*PPIX);

  __shared__ float4 s_G[MSEG];
  if (tid < MSEG) s_G[tid] = ((const float4*)(ws + OFF_GC + n*80))[tid];

  // packed (lsum, cnt_t); bin 0 is masked downstream -> accumulate m=1..15 only
  v2f lc[MSEG];
#pragma unroll
  for (int m = 0; m < MSEG; ++m) lc[m] = (v2f){0.f, 0.f};

  const int base = blk*256 + tid;
  int4 tc = textv[base];
  float4 va = pc0[base], vb = pc1[base], vc = pc2[base], vd = pc3[base];
  __syncthreads();

#define PIX2(T, A0, A1, A2, A3) do {                            \
    int t_ = (T);                                               \
    float4 gv = s_G[t_];                                        \
    float dx = (A0) - gv.x, dy = (A1) - gv.y;                   \
    float dz = (A2) - gv.z, dw = (A3) - gv.w;                   \
    float sq = fmaf(dx, dx, fmaf(dy, dy, fmaf(dz, dz, dw*dw))); \
    float dd = fmaxf(__fsqrt_rn(sq) - DELTA_AGG, 0.f);          \
    float l = __logf(fmaf(dd, dd, 1.f));                        \
    v2f l1 = {l, 1.0f};                                         \
    _Pragma("unroll")                                           \
    for (int m = 1; m < MSEG; ++m) {                            \
      float fk = (t_ == m) ? 1.0f : 0.0f;                       \
      v2f fk2 = {fk, fk};                                       \
      lc[m] = __builtin_elementwise_fma(fk2, l1, lc[m]);        \
    } } while (0)

#define GRP2(TT, VA, VB, VC, VD) do {                \
    PIX2((TT).x, (VA).x, (VB).x, (VC).x, (VD).x);    \
    PIX2((TT).y, (VA).y, (VB).y, (VC).y, (VD).y);    \
    PIX2((TT).z, (VA).z, (VB).z, (VC).z, (VD).z);    \
    PIX2((TT).w, (VA).w, (VB).w, (VC).w, (VD).w);    \
  } while (0)

  {
    const int p = base + STRIDE;
    int4 tn = textv[p];
    float4 an = pc0[p], bn = pc1[p], cn = pc2[p], dn = pc3[p];
    GRP2(tc, va, vb, vc, vd);
    tc = tn; va = an; vb = bn; vc = cn; vd = dn;
  }
  {
    const int p = base + 2*STRIDE;
    int4 tn = textv[p];
    float4 an = pc0[p], bn = pc1[p], cn = pc2[p], dn = pc3[p];
    GRP2(tc, va, vb, vc, vd);
    tc = tn; va = an; vb = bn; vc = cn; vd = dn;
  }
  {
    int4 tr; float4 ar, br, cr, dr;
    const int pr = FULLCOV + blk*32 + (tid & 31);
    if (tid < 32) { tr = textv[pr]; ar = pc0[pr]; br = pc1[pr]; cr = pc2[pr]; dr = pc3[pr]; }
    GRP2(tc, va, vb, vc, vd);
    if (tid < 32) GRP2(tr, ar, br, cr, dr);
  }
#undef GRP2
#undef PIX2

  float ls[MSEG], ct[MSEG];
#pragma unroll
  for (int m = 0; m < MSEG; ++m) { ls[m] = lc[m].x; ct[m] = lc[m].y; }

  float t0, t1;
#pragma unroll
  for (int s = 0; s < 4; ++s) {
    const int dist = 32 >> s; const int half = 8 >> s;
    const bool hi = (lane & dist) != 0;
#pragma unroll
    for (int v = 0; v < half; ++v) {
      float keep = hi ? ls[v + half] : ls[v];
      float send = hi ? ls[v] : ls[v + half];
      ls[v] = keep + __shfl_xor(send, dist);
    }
  }
  t0 = ls[0]; t0 += __shfl_xor(t0, 2); t0 += __shfl_xor(t0, 1);
#pragma unroll
  for (int s = 0; s < 4; ++s) {
    const int dist = 32 >> s; const int half = 8 >> s;
    const bool hi = (lane & dist) != 0;
#pragma unroll
    for (int v = 0; v < half; ++v) {
      float keep = hi ? ct[v + half] : ct[v];
      float send = hi ? ct[v] : ct[v + half];
      ct[v] = keep + __shfl_xor(send, dist);
    }
  }
  t1 = ct[0]; t1 += __shfl_xor(t1, 2); t1 += __shfl_xor(t1, 1);

  __shared__ float s_l[4][16];
  __shared__ float s_t[4][16];
  if ((lane & 3) == 0) { s_l[w][lane >> 2] = t0; s_t[w][lane >> 2] = t1; }
  __syncthreads();

  if (tid < 16)
    ws[OFF_P2 + ((size_t)n*32 + tid)*GRIDX + blk] =
        s_l[0][tid] + s_l[1][tid] + s_l[2][tid] + s_l[3][tid];
  else if (tid < 32) {
    int i = tid - 16;
    ws[OFF_P2 + ((size_t)n*32 + tid)*GRIDX + blk] =
        s_t[0][i] + s_t[1][i] + s_t[2][i] + s_t[3][i];
  }

  // last block of this batch computes the final outputs
  __threadfence();
  __shared__ int s_last;
  if (tid == 0) s_last = (atomicAdd(&ctr[NB + n], 1) == GRIDX - 1);
  __syncthreads();
  if (!s_last) return;
  __threadfence();

  __shared__ float s2[32];        // 0..15 lsum, 16..31 cnt_t
  __shared__ float sG[MSEG][4];
  __shared__ float sck[MSEG];
  __shared__ int   sval[MSEG];
  __shared__ int   snv;
  __shared__ float red[256];
  __shared__ float agg_sum;

  if (tid < 32) {
    const float4* p4 = (const float4*)(ws + OFF_P2 + ((size_t)n*32 + tid)*GRIDX);
    float s = 0.f;
#pragma unroll
    for (int i = 0; i < GRIDX/4; ++i) {
      float4 v = p4[i];
      s += (v.x + v.y) + (v.z + v.w);
    }
    s2[tid] = s;
  } else if (tid >= 32 && tid < 48) {
    sck[tid - 32] = ws[OFF_GC + n*80 + 64 + (tid - 32)];
  } else if (tid >= 64 && tid < 128) {
    int i = tid - 64;
    sG[i >> 2][i & 3] = ws[OFF_GC + n*80 + i];
  }
  __syncthreads();
  if (tid < MSEG)
    sval[tid] = (tid >= 1) && (sck[tid] > 0.f) && (s2[16 + tid] > 0.f);
  __syncthreads();
  if (tid == 0) { int nv = 0; for (int m = 0; m < MSEG; m++) nv += sval[m]; snv = nv; }

  float av = 0.f;
  if (tid < MSEG && sval[tid]) av = s2[tid] / fmaxf(s2[16 + tid], 1.0f);
  red[tid] = av;
  __syncthreads();
  for (int s = 128; s > 0; s >>= 1) {
    if (tid < s) red[tid] += red[tid + s];
    __syncthreads();
  }
  if (tid == 0) agg_sum = red[0];
  __syncthreads();

  float lp = 0.f;
  {
    int i = tid >> 4, j = tid & 15;
    if (i != j && sval[i] && sval[j]) {
      float dx = sG[i][0] - sG[j][0];
      float dy = sG[i][1] - sG[j][1];
      float dz = sG[i][2] - sG[j][2];
      float dw = sG[i][3] - sG[j][3];
      float dist = sqrtf(dx*dx + dy*dy + dz*dz + dw*dw);
      float t = fmaxf(DELTA_DIS - dist, 0.f);
      lp = logf(t*t + 1.f);
    }
  }
  red[tid] = lp;
  __syncthreads();
  for (int s = 128; s > 0; s >>= 1) {
    if (tid < s) red[tid] += red[tid + s];
    __syncthreads();
  }
  if (tid == 0) {
    int nv = snv;
    out[n] = agg_sum / (float)(nv > 1 ? nv : 1);
    out[NB + n] = (nv > 1) ? 0.5f * red[0] / (float)(nv * (nv - 1)) : 0.f;
  }
}

extern "C" void kernel_launch(void* const* d_in, const int* in_sizes, int n_in,
                              void* d_out, int out_size, void* d_ws, size_t ws_size,
                              hipStream_t stream) {
  const float* preds   = (const float*)d_in[0];
  const int*   targets = (const int*)d_in[1];
  float* out = (float*)d_out;
  float* ws  = (float*)d_ws;
  int*   ctr = (int*)d_ws;

  hipMemsetAsync(d_ws, 0, 64, stream);   // 16 int counters only

  dim3 grid(GRIDX, NB);
  pass1_kernel<<<grid, 256, 0, stream>>>(preds, targets, ws, ctr);
  pass2_kernel<<<grid, 256, 0, stream>>>(preds, targets, ws, ctr, out);
}

// Round 9
// 54.757 us; speedup vs baseline: 4.2869x; 4.2869x over previous
//
#include <hip/hip_runtime.h>
#include <math.h>

#define NB 8
#define MSEG 16
#define PPIX (640*640)
#define PV4 (PPIX/4)          // 102400 float4/int4 groups per batch
#define GRIDX 128             // 1024 blocks total
#define STRIDE (GRIDX*256)    // 32768; 3 full iters = 98304, remainder 4096
#define FULLCOV (3*STRIDE)    // 98304
#define DELTA_AGG 0.5f
#define DELTA_DIS 3.0f

typedef float v2f __attribute__((ext_vector_type(2)));

// ws float layout (atomic accumulators zeroed by in-graph 3.6KB memset)
#define OFF_A1 0              // [NB][80]: 0..63 kern-sums (ch*16+m), 64..79 cnt_k
#define OFF_A2 (NB*80)        // [NB][32]: 0..15 lsum, 16..31 cnt_t
#define WS_ZERO_FLOATS (NB*112)

// ---------------- pass 1: register-binned segment sums by kern ----------------
__global__ __launch_bounds__(256, 3) void pass1_kernel(
    const float* __restrict__ preds, const int* __restrict__ targets,
    float* __restrict__ ws) {
  const int n = blockIdx.y, blk = blockIdx.x;
  const int tid = threadIdx.x, lane = tid & 63, w = tid >> 6;

  const float4* __restrict__ pc0 = (const float4*)(preds + ((size_t)n*6 + 2)*PPIX);
  const float4* __restrict__ pc1 = (const float4*)(preds + ((size_t)n*6 + 3)*PPIX);
  const float4* __restrict__ pc2 = (const float4*)(preds + ((size_t)n*6 + 4)*PPIX);
  const float4* __restrict__ pc3 = (const float4*)(preds + ((size_t)n*6 + 5)*PPIX);
  const int4*  __restrict__ kernv = (const int4*)(targets + ((size_t)n*2 + 1)*PPIX);

  // packed accumulators; bin 0 never accumulated (masked downstream, G[0]=0/1)
  v2f acc01[MSEG], acc23[MSEG];
  float cntk[MSEG];
#pragma unroll
  for (int m = 0; m < MSEG; ++m) {
    acc01[m] = (v2f){0.f, 0.f}; acc23[m] = (v2f){0.f, 0.f}; cntk[m] = 0.f;
  }

#define PIX1(K, A0, A1, A2, A3) do {                                \
    int k_ = (K);                                                   \
    v2f p01 = {(A0), (A1)}, p23 = {(A2), (A3)};                     \
    _Pragma("unroll")                                               \
    for (int m = 1; m < MSEG; ++m) {                                \
      float fk = (k_ == m) ? 1.0f : 0.0f;                           \
      v2f fk2 = {fk, fk};                                           \
      acc01[m] = __builtin_elementwise_fma(fk2, p01, acc01[m]);     \
      acc23[m] = __builtin_elementwise_fma(fk2, p23, acc23[m]);     \
      cntk[m] += fk;                                                \
    } } while (0)

#define GRP1(KK, VA, VB, VC, VD) do {                \
    PIX1((KK).x, (VA).x, (VB).x, (VC).x, (VD).x);    \
    PIX1((KK).y, (VA).y, (VB).y, (VC).y, (VD).y);    \
    PIX1((KK).z, (VA).z, (VB).z, (VC).z, (VD).z);    \
    PIX1((KK).w, (VA).w, (VB).w, (VC).w, (VD).w);    \
  } while (0)

  const int base = blk*256 + tid;
  int4 kc = kernv[base];
  float4 va = pc0[base], vb = pc1[base], vc = pc2[base], vd = pc3[base];
  {
    const int p = base + STRIDE;
    int4 kn = kernv[p];
    float4 an = pc0[p], bn = pc1[p], cn = pc2[p], dn = pc3[p];
    GRP1(kc, va, vb, vc, vd);
    kc = kn; va = an; vb = bn; vc = cn; vd = dn;
  }
  {
    const int p = base + 2*STRIDE;
    int4 kn = kernv[p];
    float4 an = pc0[p], bn = pc1[p], cn = pc2[p], dn = pc3[p];
    GRP1(kc, va, vb, vc, vd);
    kc = kn; va = an; vb = bn; vc = cn; vd = dn;
  }
  {
    int4 kr; float4 ar, br, cr, dr;
    const int pr = FULLCOV + blk*32 + (tid & 31);
    if (tid < 32) { kr = kernv[pr]; ar = pc0[pr]; br = pc1[pr]; cr = pc2[pr]; dr = pc3[pr]; }
    GRP1(kc, va, vb, vc, vd);
    if (tid < 32) GRP1(kr, ar, br, cr, dr);
  }
#undef GRP1
#undef PIX1

  float acc[80];
#pragma unroll
  for (int m = 0; m < MSEG; ++m) {
    acc[m]      = acc01[m].x;
    acc[16 + m] = acc01[m].y;
    acc[32 + m] = acc23[m].x;
    acc[48 + m] = acc23[m].y;
    acc[64 + m] = cntk[m];
  }

  // 64-value xor reduce-scatter: lane l ends holding the 64-lane sum of acc[l]
#pragma unroll
  for (int s = 0; s < 6; ++s) {
    const int dist = 32 >> s;
    const bool hi = (lane & dist) != 0;
#pragma unroll
    for (int v = 0; v < (32 >> s); ++v) {
      float keep = hi ? acc[v + (32 >> s)] : acc[v];
      float send = hi ? acc[v] : acc[v + (32 >> s)];
      acc[v] = keep + __shfl_xor(send, dist);
    }
  }
  // 16-value reduce-scatter on cnt_k: 4-lane group g ends holding cnt_k[g]
  float cn16[16];
#pragma unroll
  for (int m = 0; m < MSEG; ++m) cn16[m] = acc[64 + m];
#pragma unroll
  for (int s = 0; s < 4; ++s) {
    const int dist = 32 >> s;
    const int half = 8 >> s;
    const bool hi = (lane & dist) != 0;
#pragma unroll
    for (int v = 0; v < half; ++v) {
      float keep = hi ? cn16[v + half] : cn16[v];
      float send = hi ? cn16[v] : cn16[v + half];
      cn16[v] = keep + __shfl_xor(send, dist);
    }
  }
  float ckt = cn16[0];
  ckt += __shfl_xor(ckt, 2);
  ckt += __shfl_xor(ckt, 1);

  __shared__ float s_v[4][64];
  __shared__ float s_c[4][16];
  s_v[w][lane] = acc[0];
  if ((lane & 3) == 0) s_c[w][lane >> 2] = ckt;
  __syncthreads();

  if (tid < 64) {
    atomicAdd(&ws[OFF_A1 + n*80 + tid],
              s_v[0][tid] + s_v[1][tid] + s_v[2][tid] + s_v[3][tid]);
  } else if (tid < 80) {
    int i = tid - 64;
    atomicAdd(&ws[OFF_A1 + n*80 + tid],
              s_c[0][i] + s_c[1][i] + s_c[2][i] + s_c[3][i]);
  }
}

// ---------------- pass 2: agg sums + cnt_t by text (G computed per-block) ----------------
__global__ __launch_bounds__(256, 4) void pass2_kernel(
    const float* __restrict__ preds, const int* __restrict__ targets,
    float* __restrict__ ws) {
  const int n = blockIdx.y, blk = blockIdx.x;
  const int tid = threadIdx.x, lane = tid & 63, w = tid >> 6;

  const float4* __restrict__ pc0 = (const float4*)(preds + ((size_t)n*6 + 2)*PPIX);
  const float4* __restrict__ pc1 = (const float4*)(preds + ((size_t)n*6 + 3)*PPIX);
  const float4* __restrict__ pc2 = (const float4*)(preds + ((size_t)n*6 + 4)*PPIX);
  const float4* __restrict__ pc3 = (const float4*)(preds + ((size_t)n*6 + 5)*PPIX);
  const int4*  __restrict__ textv = (const int4*)(targets + (size_t)n*2*PPIX);

  // issue first-iteration loads before the G preamble (independent)
  const int base = blk*256 + tid;
  int4 tc = textv[base];
  float4 va = pc0[base], vb = pc1[base], vc = pc2[base], vd = pc3[base];

  // per-block G recompute from raw atomic sums (replaces finalize_G dispatch)
  __shared__ float s_raw[80];
  __shared__ float4 s_G[MSEG];
  if (tid < 80) s_raw[tid] = ws[OFF_A1 + n*80 + tid];
  __syncthreads();
  if (tid < 64) {
    int ch = tid >> 4, m = tid & 15;
    ((float*)&s_G[m])[ch] = s_raw[ch*16 + m] / fmaxf(s_raw[64 + m], 1.0f);
  }
  __syncthreads();

  // packed (lsum, cnt_t); bin 0 masked downstream -> accumulate m=1..15 only
  v2f lc[MSEG];
#pragma unroll
  for (int m = 0; m < MSEG; ++m) lc[m] = (v2f){0.f, 0.f};

#define PIX2(T, A0, A1, A2, A3) do {                            \
    int t_ = (T);                                               \
    float4 gv = s_G[t_];                                        \
    float dx = (A0) - gv.x, dy = (A1) - gv.y;                   \
    float dz = (A2) - gv.z, dw = (A3) - gv.w;                   \
    float sq = fmaf(dx, dx, fmaf(dy, dy, fmaf(dz, dz, dw*dw))); \
    float dd = fmaxf(__fsqrt_rn(sq) - DELTA_AGG, 0.f);          \
    float l = __logf(fmaf(dd, dd, 1.f));                        \
    v2f l1 = {l, 1.0f};                                         \
    _Pragma("unroll")                                           \
    for (int m = 1; m < MSEG; ++m) {                            \
      float fk = (t_ == m) ? 1.0f : 0.0f;                       \
      v2f fk2 = {fk, fk};                                       \
      lc[m] = __builtin_elementwise_fma(fk2, l1, lc[m]);        \
    } } while (0)

#define GRP2(TT, VA, VB, VC, VD) do {                \
    PIX2((TT).x, (VA).x, (VB).x, (VC).x, (VD).x);    \
    PIX2((TT).y, (VA).y, (VB).y, (VC).y, (VD).y);    \
    PIX2((TT).z, (VA).z, (VB).z, (VC).z, (VD).z);    \
    PIX2((TT).w, (VA).w, (VB).w, (VC).w, (VD).w);    \
  } while (0)

  {
    const int p = base + STRIDE;
    int4 tn = textv[p];
    float4 an = pc0[p], bn = pc1[p], cn = pc2[p], dn = pc3[p];
    GRP2(tc, va, vb, vc, vd);
    tc = tn; va = an; vb = bn; vc = cn; vd = dn;
  }
  {
    const int p = base + 2*STRIDE;
    int4 tn = textv[p];
    float4 an = pc0[p], bn = pc1[p], cn = pc2[p], dn = pc3[p];
    GRP2(tc, va, vb, vc, vd);
    tc = tn; va = an; vb = bn; vc = cn; vd = dn;
  }
  {
    int4 tr; float4 ar, br, cr, dr;
    const int pr = FULLCOV + blk*32 + (tid & 31);
    if (tid < 32) { tr = textv[pr]; ar = pc0[pr]; br = pc1[pr]; cr = pc2[pr]; dr = pc3[pr]; }
    GRP2(tc, va, vb, vc, vd);
    if (tid < 32) GRP2(tr, ar, br, cr, dr);
  }
#undef GRP2
#undef PIX2

  float ls[MSEG], ct[MSEG];
#pragma unroll
  for (int m = 0; m < MSEG; ++m) { ls[m] = lc[m].x; ct[m] = lc[m].y; }

  float t0, t1;
#pragma unroll
  for (int s = 0; s < 4; ++s) {
    const int dist = 32 >> s; const int half = 8 >> s;
    const bool hi = (lane & dist) != 0;
#pragma unroll
    for (int v = 0; v < half; ++v) {
      float keep = hi ? ls[v + half] : ls[v];
      float send = hi ? ls[v] : ls[v + half];
      ls[v] = keep + __shfl_xor(send, dist);
    }
  }
  t0 = ls[0]; t0 += __shfl_xor(t0, 2); t0 += __shfl_xor(t0, 1);
#pragma unroll
  for (int s = 0; s < 4; ++s) {
    const int dist = 32 >> s; const int half = 8 >> s;
    const bool hi = (lane & dist) != 0;
#pragma unroll
    for (int v = 0; v < half; ++v) {
      float keep = hi ? ct[v + half] : ct[v];
      float send = hi ? ct[v] : ct[v + half];
      ct[v] = keep + __shfl_xor(send, dist);
    }
  }
  t1 = ct[0]; t1 += __shfl_xor(t1, 2); t1 += __shfl_xor(t1, 1);

  __shared__ float s_l[4][16];
  __shared__ float s_t[4][16];
  if ((lane & 3) == 0) { s_l[w][lane >> 2] = t0; s_t[w][lane >> 2] = t1; }
  __syncthreads();

  if (tid < 16)
    atomicAdd(&ws[OFF_A2 + n*32 + tid],
              s_l[0][tid] + s_l[1][tid] + s_l[2][tid] + s_l[3][tid]);
  else if (tid < 32) {
    int i = tid - 16;
    atomicAdd(&ws[OFF_A2 + n*32 + tid],
              s_t[0][i] + s_t[1][i] + s_t[2][i] + s_t[3][i]);
  }
}

// ------------- finalize: agg + dis (one block/batch, reads raw sums) -------------
__global__ __launch_bounds__(256) void finalize2_kernel(
    const float* __restrict__ ws, float* __restrict__ out) {
  const int n = blockIdx.x;
  const int tid = threadIdx.x;

  __shared__ float raw1[80];      // 0..63 kern-sums, 64..79 cnt_k
  __shared__ float s2[32];        // 0..15 lsum, 16..31 cnt_t
  __shared__ float sG[MSEG][4];
  __shared__ int   sval[MSEG];
  __shared__ int   snv;
  __shared__ float red[256];
  __shared__ float agg_sum;

  if (tid < 80) raw1[tid] = ws[OFF_A1 + n*80 + tid];
  else if (tid >= 96 && tid < 128) s2[tid - 96] = ws[OFF_A2 + n*32 + (tid - 96)];
  __syncthreads();
  if (tid < 64) {
    int ch = tid >> 4, m = tid & 15;
    sG[m][ch] = raw1[ch*16 + m] / fmaxf(raw1[64 + m], 1.0f);
  }
  if (tid < MSEG)
    sval[tid] = (tid >= 1) && (raw1[64 + tid] > 0.f) && (s2[16 + tid] > 0.f);
  __syncthreads();
  if (tid == 0) { int nv = 0; for (int m = 0; m < MSEG; m++) nv += sval[m]; snv = nv; }

  float av = 0.f;
  if (tid < MSEG && sval[tid]) av = s2[tid] / fmaxf(s2[16 + tid], 1.0f);
  red[tid] = av;
  __syncthreads();
  for (int s = 128; s > 0; s >>= 1) {
    if (tid < s) red[tid] += red[tid + s];
    __syncthreads();
  }
  if (tid == 0) agg_sum = red[0];
  __syncthreads();

  float lp = 0.f;
  {
    int i = tid >> 4, j = tid & 15;
    if (i != j && sval[i] && sval[j]) {
      float dx = sG[i][0] - sG[j][0];
      float dy = sG[i][1] - sG[j][1];
      float dz = sG[i][2] - sG[j][2];
      float dw = sG[i][3] - sG[j][3];
      float dist = sqrtf(dx*dx + dy*dy + dz*dz + dw*dw);
      float t = fmaxf(DELTA_DIS - dist, 0.f);
      lp = logf(t*t + 1.f);
    }
  }
  red[tid] = lp;
  __syncthreads();
  for (int s = 128; s > 0; s >>= 1) {
    if (tid < s) red[tid] += red[tid + s];
    __syncthreads();
  }
  if (tid == 0) {
    int nv = snv;
    out[n] = agg_sum / (float)(nv > 1 ? nv : 1);
    out[NB + n] = (nv > 1) ? 0.5f * red[0] / (float)(nv * (nv - 1)) : 0.f;
  }
}

extern "C" void kernel_launch(void* const* d_in, const int* in_sizes, int n_in,
                              void* d_out, int out_size, void* d_ws, size_t ws_size,
                              hipStream_t stream) {
  const float* preds   = (const float*)d_in[0];
  const int*   targets = (const int*)d_in[1];
  float* out = (float*)d_out;
  float* ws  = (float*)d_ws;

  hipMemsetAsync(d_ws, 0, WS_ZERO_FLOATS * sizeof(float), stream);

  dim3 grid(GRIDX, NB);
  pass1_kernel<<<grid, 256, 0, stream>>>(preds, targets, ws);
  pass2_kernel<<<grid, 256, 0, stream>>>(preds, targets, ws);
  finalize2_kernel<<<NB, 256, 0, stream>>>(ws, out);
}